// Round 14
// baseline (168.396 us; speedup 1.0000x reference)
//
#include <hip/hip_runtime.h>
#include <cstdint>
#include <cstddef>

#define BSZ 16
#define NN  256
#define DE  64
#define DXX 256
#define FAN (4 * DE)   // 256
#define IB  4          // rows (b,i) per block

// ---------------------------------------------------------------------------
// Prologue: blocks 0..255 transpose W (DXX x FAN) -> WT (FAN x DXX, f32);
// block 256 detects mask dtype (u8/i32/f32) and normalizes to maskf[4096].
// ---------------------------------------------------------------------------
__global__ __launch_bounds__(256) void prep_kernel(
    const uint8_t* __restrict__ raw, const float* __restrict__ W,
    float* __restrict__ WT, float* __restrict__ maskf)
{
    const int t   = threadIdx.x;
    const int blk = blockIdx.x;
    if (blk < FAN) {
        WT[blk * DXX + t] = W[t * FAN + blk];   // WT[f][dx] = W[dx][f]
    } else {
        __shared__ int det[2];
        if (t == 0) { det[0] = 0; det[1] = 0; }
        __syncthreads();
        int s1 = 0, s23 = 0;
        const uint8_t* p = raw + t * 16;
        #pragma unroll
        for (int u = 0; u < 16; ++u) {
            int v = (int)p[u];
            int m4 = u & 3;
            if (m4 == 1) s1 += v; else if (m4 >= 2) s23 += v;
        }
        if (s1)  atomicAdd(&det[0], s1);
        if (s23) atomicAdd(&det[1], s23);
        __syncthreads();
        const int kind = (det[1] == 0) ? 1 : ((det[0] == 0) ? 2 : 0);  // 1=i32,2=f32,0=u8
        for (int idx = t; idx < BSZ * NN; idx += 256) {
            float mv;
            if (kind == 1)      mv = (((const int*)(const void*)raw)[idx] != 0) ? 1.f : 0.f;
            else if (kind == 2) mv = (((const float*)(const void*)raw)[idx] != 0.f) ? 1.f : 0.f;
            else                mv = (raw[idx] != 0) ? 1.f : 0.f;
            maskf[idx] = mv;
        }
    }
}

// ---------------------------------------------------------------------------
// Producer-consumer main kernel. 320 threads = 5 waves.
// Waves 0-3 (t<256): EXACT R12 streaming reduction (phase B), unchanged.
// Wave 4 (t>=256): consumer — during row r+1's streaming window it computes
// row r's full matvec (own per-wave vmcnt queue: WT loads never interact with
// producer E-prefetch pipelines) and stores out directly with bias.
// Tail = row 3's matvec (~1.7us). No part_c, no epilogue pass.
// ---------------------------------------------------------------------------
__global__ __launch_bounds__(320, 5) void etox_pc(
    const float* __restrict__ E, const float* __restrict__ maskf,
    const float* __restrict__ WT, const float* __restrict__ bias,
    float* __restrict__ out)
{
    __shared__ float m_lds[NN];
    __shared__ float cpart[4];
    __shared__ float partial[4][16][20];   // [wave][dquad][acc] 5 KB
    __shared__ float z_lds[IB][FAN];       // 4 KB

    const int t      = threadIdx.x;
    const int g0     = blockIdx.x * IB;    // global row = b*NN + i
    const int b      = g0 >> 8;
    const int wv     = t >> 6;             // 0..4
    const int lane   = t & 63;
    const bool cons  = (t >= 256);         // wave 4 = consumer

    // ---- phase A: mask row + count (producers only) ----
    if (!cons) {
        float mv = maskf[b * NN + t];
        m_lds[t] = mv;
        unsigned long long bal = __ballot(mv != 0.f);
        if (lane == 0) cpart[wv] = (float)__popcll(bal);
    }
    __syncthreads();
    const float inv_cnt = 1.0f / (cpart[0] + cpart[1] + cpart[2] + cpart[3]);

    // consumer setup
    const float4* WT4 = (const float4*)WT;
    float4 bv4 = make_float4(0.f, 0.f, 0.f, 0.f);
    if (cons) bv4 = *(const float4*)(bias + 4 * lane);

    // producer setup
    const int dq = t & 15;                 // d = 4*dq .. 4*dq+3
    const int jb = t >> 4;                 // j = jb + 16*k, k = 0..15
    const float* base0 = E + (size_t)g0 * (NN * DE) + (size_t)jb * DE + 4 * dq;

    #define LD(P, K) (*(const float4*)((P) + (size_t)(K) * (16 * DE)))
    float4 A0, A1, A2, A3, B0, B1, B2, B3;
    if (!cons) { A0 = LD(base0, 0); A1 = LD(base0, 1); A2 = LD(base0, 2); A3 = LD(base0, 3); }

    // consumer matvec for one row (full 256-f dot per lane; dx = 4*lane..4*lane+3)
    #define CONS_MV(RZ, DEST_ROW) { \
        float4 acc = make_float4(0.f, 0.f, 0.f, 0.f); \
        _Pragma("unroll 4") \
        for (int f = 0; f < FAN; f += 4) { \
            float4 w0 = WT4[(size_t)(f + 0) * 64 + lane]; \
            float4 w1 = WT4[(size_t)(f + 1) * 64 + lane]; \
            float4 w2 = WT4[(size_t)(f + 2) * 64 + lane]; \
            float4 w3 = WT4[(size_t)(f + 3) * 64 + lane]; \
            float4 z4 = *(const float4*)(&z_lds[RZ][f]); \
            acc.x = fmaf(z4.x, w0.x, fmaf(z4.y, w1.x, fmaf(z4.z, w2.x, fmaf(z4.w, w3.x, acc.x)))); \
            acc.y = fmaf(z4.x, w0.y, fmaf(z4.y, w1.y, fmaf(z4.z, w2.y, fmaf(z4.w, w3.y, acc.y)))); \
            acc.z = fmaf(z4.x, w0.z, fmaf(z4.y, w1.z, fmaf(z4.z, w2.z, fmaf(z4.w, w3.z, acc.z)))); \
            acc.w = fmaf(z4.x, w0.w, fmaf(z4.y, w1.w, fmaf(z4.z, w2.w, fmaf(z4.w, w3.w, acc.w)))); \
        } \
        acc.x += bv4.x; acc.y += bv4.y; acc.z += bv4.z; acc.w += bv4.w; \
        *(float4*)(out + (size_t)(g0 + (DEST_ROW)) * DXX + 4 * lane) = acc; \
    }

    for (int r = 0; r < IB; ++r) {
        if (!cons) {
            const float* baser = base0 + (size_t)r * (NN * DE);

            float s[4]  = {0.f, 0.f, 0.f, 0.f};
            float ms[4] = {0.f, 0.f, 0.f, 0.f};
            float q[4]  = {0.f, 0.f, 0.f, 0.f};
            float mi[4] = {1e30f, 1e30f, 1e30f, 1e30f};
            float ma[4] = {-1e30f, -1e30f, -1e30f, -1e30f};

            #define CONS1(V, KK) { \
                float mk = m_lds[jb + 16 * (KK)]; \
                bool on = (mk != 0.f); \
                float4 v = V; \
                s[0] += v.x; s[1] += v.y; s[2] += v.z; s[3] += v.w; \
                ms[0] = fmaf(mk, v.x, ms[0]); ms[1] = fmaf(mk, v.y, ms[1]); \
                ms[2] = fmaf(mk, v.z, ms[2]); ms[3] = fmaf(mk, v.w, ms[3]); \
                q[0] = fmaf(mk * v.x, v.x, q[0]); q[1] = fmaf(mk * v.y, v.y, q[1]); \
                q[2] = fmaf(mk * v.z, v.z, q[2]); q[3] = fmaf(mk * v.w, v.w, q[3]); \
                mi[0] = fminf(mi[0], on ? v.x : 1e30f); mi[1] = fminf(mi[1], on ? v.y : 1e30f); \
                mi[2] = fminf(mi[2], on ? v.z : 1e30f); mi[3] = fminf(mi[3], on ? v.w : 1e30f); \
                ma[0] = fmaxf(ma[0], on ? v.x : -1e30f); ma[1] = fmaxf(ma[1], on ? v.y : -1e30f); \
                ma[2] = fmaxf(ma[2], on ? v.z : -1e30f); ma[3] = fmaxf(ma[3], on ? v.w : -1e30f); \
            }

            B0 = LD(baser, 4);  B1 = LD(baser, 5);  B2 = LD(baser, 6);  B3 = LD(baser, 7);
            CONS1(A0, 0) CONS1(A1, 1) CONS1(A2, 2) CONS1(A3, 3)
            A0 = LD(baser, 8);  A1 = LD(baser, 9);  A2 = LD(baser, 10); A3 = LD(baser, 11);
            CONS1(B0, 4) CONS1(B1, 5) CONS1(B2, 6) CONS1(B3, 7)
            B0 = LD(baser, 12); B1 = LD(baser, 13); B2 = LD(baser, 14); B3 = LD(baser, 15);
            CONS1(A0, 8) CONS1(A1, 9) CONS1(A2, 10) CONS1(A3, 11)
            if (r < IB - 1) {
                const float* basen = baser + (NN * DE);
                A0 = LD(basen, 0); A1 = LD(basen, 1); A2 = LD(basen, 2); A3 = LD(basen, 3);
            }
            CONS1(B0, 12) CONS1(B1, 13) CONS1(B2, 14) CONS1(B3, 15)
            #undef CONS1

            #pragma unroll
            for (int c = 0; c < 4; ++c) {
                s[c]  += __shfl_xor(s[c], 16);  s[c]  += __shfl_xor(s[c], 32);
                ms[c] += __shfl_xor(ms[c], 16); ms[c] += __shfl_xor(ms[c], 32);
                q[c]  += __shfl_xor(q[c], 16);  q[c]  += __shfl_xor(q[c], 32);
                mi[c] = fminf(mi[c], __shfl_xor(mi[c], 16));
                mi[c] = fminf(mi[c], __shfl_xor(mi[c], 32));
                ma[c] = fmaxf(ma[c], __shfl_xor(ma[c], 16));
                ma[c] = fmaxf(ma[c], __shfl_xor(ma[c], 32));
            }

            if (lane < 16) {
                float* p = partial[wv][lane];
                #pragma unroll
                for (int c = 0; c < 4; ++c) {
                    p[c]      = s[c];
                    p[4 + c]  = ms[c];
                    p[8 + c]  = q[c];
                    p[12 + c] = mi[c];
                    p[16 + c] = ma[c];
                }
            }
        } else {
            // consumer: matvec of PREVIOUS row while producers stream row r
            if (r > 0) CONS_MV(r - 1, r - 1)
        }
        __syncthreads();   // A(r): partial complete (consumer arrives early)

        if (t < 64) {
            const int d = t, dq2 = d >> 2, c = d & 3;
            float ss = 0.f, mss = 0.f, mq = 0.f, lmi = 1e30f, lma = -1e30f;
            #pragma unroll
            for (int w = 0; w < 4; ++w) {
                const float* p = partial[w][dq2];
                ss  += p[c];
                mss += p[4 + c];
                mq  += p[8 + c];
                lmi  = fminf(lmi, p[12 + c]);
                lma  = fmaxf(lma, p[16 + c]);
            }
            float m    = ss * inv_cnt;
            float stdv = mq * inv_cnt - 2.0f * m * (mss * inv_cnt) + m * m;
            z_lds[r][d]       = m;
            z_lds[r][64 + d]  = lmi;
            z_lds[r][128 + d] = lma;
            z_lds[r][192 + d] = stdv;
        }
        __syncthreads();   // B(r): z_lds[r] visible; partial reusable
    }
    #undef LD

    // tail: consumer does the last row's matvec
    if (cons) CONS_MV(IB - 1, IB - 1)
    #undef CONS_MV
}

// ---------------------------------------------------------------------------
// Legacy fallback (ws too small): R12 single-kernel path, inline mask detect.
// ---------------------------------------------------------------------------
__global__ __launch_bounds__(256, 4) void etox_legacy(
    const float* __restrict__ E, const uint8_t* __restrict__ raw,
    const float* __restrict__ W, const float* __restrict__ bias,
    float* __restrict__ out)
{
    __shared__ float m_lds[NN];
    __shared__ int   det[2];
    __shared__ float cpart[4];
    __shared__ float partial[4][16][20];
    __shared__ float z_lds[IB][FAN];

    const int t    = threadIdx.x;
    const int g0   = blockIdx.x * IB;
    const int b    = g0 >> 8;
    const int wv   = t >> 6;
    const int lane = t & 63;

    if (t == 0) { det[0] = 0; det[1] = 0; }
    int s1 = 0, s23 = 0;
    {
        const uint8_t* p = raw + t * 16;
        #pragma unroll
        for (int u = 0; u < 16; ++u) {
            int v = (int)p[u];
            int m4 = u & 3;
            if (m4 == 1) s1 += v; else if (m4 >= 2) s23 += v;
        }
    }
    __syncthreads();
    if (s1)  atomicAdd(&det[0], s1);
    if (s23) atomicAdd(&det[1], s23);
    __syncthreads();
    const int kind = (det[1] == 0) ? 1 : ((det[0] == 0) ? 2 : 0);
    float mv;
    {
        int idx = b * NN + t;
        if (kind == 1)      mv = (((const int*)(const void*)raw)[idx] != 0) ? 1.f : 0.f;
        else if (kind == 2) mv = (((const float*)(const void*)raw)[idx] != 0.f) ? 1.f : 0.f;
        else                mv = (raw[idx] != 0) ? 1.f : 0.f;
    }
    m_lds[t] = mv;
    unsigned long long bal = __ballot(mv != 0.f);
    if (lane == 0) cpart[wv] = (float)__popcll(bal);
    __syncthreads();
    const float inv_cnt = 1.0f / (cpart[0] + cpart[1] + cpart[2] + cpart[3]);

    const int dq = t & 15;
    const int jb = t >> 4;
    const float* base0 = E + (size_t)g0 * (NN * DE) + (size_t)jb * DE + 4 * dq;

    #define LD(P, K) (*(const float4*)((P) + (size_t)(K) * (16 * DE)))
    float4 A0, A1, A2, A3, B0, B1, B2, B3;
    A0 = LD(base0, 0); A1 = LD(base0, 1); A2 = LD(base0, 2); A3 = LD(base0, 3);

    for (int r = 0; r < IB; ++r) {
        const float* baser = base0 + (size_t)r * (NN * DE);
        float s[4]  = {0.f, 0.f, 0.f, 0.f};
        float ms[4] = {0.f, 0.f, 0.f, 0.f};
        float q[4]  = {0.f, 0.f, 0.f, 0.f};
        float mi[4] = {1e30f, 1e30f, 1e30f, 1e30f};
        float ma[4] = {-1e30f, -1e30f, -1e30f, -1e30f};

        #define CONS1(V, KK) { \
            float mkv = m_lds[jb + 16 * (KK)]; \
            bool on = (mkv != 0.f); \
            float4 v = V; \
            s[0] += v.x; s[1] += v.y; s[2] += v.z; s[3] += v.w; \
            ms[0] = fmaf(mkv, v.x, ms[0]); ms[1] = fmaf(mkv, v.y, ms[1]); \
            ms[2] = fmaf(mkv, v.z, ms[2]); ms[3] = fmaf(mkv, v.w, ms[3]); \
            q[0] = fmaf(mkv * v.x, v.x, q[0]); q[1] = fmaf(mkv * v.y, v.y, q[1]); \
            q[2] = fmaf(mkv * v.z, v.z, q[2]); q[3] = fmaf(mkv * v.w, v.w, q[3]); \
            mi[0] = fminf(mi[0], on ? v.x : 1e30f); mi[1] = fminf(mi[1], on ? v.y : 1e30f); \
            mi[2] = fminf(mi[2], on ? v.z : 1e30f); mi[3] = fminf(mi[3], on ? v.w : 1e30f); \
            ma[0] = fmaxf(ma[0], on ? v.x : -1e30f); ma[1] = fmaxf(ma[1], on ? v.y : -1e30f); \
            ma[2] = fmaxf(ma[2], on ? v.z : -1e30f); ma[3] = fmaxf(ma[3], on ? v.w : -1e30f); \
        }

        B0 = LD(baser, 4);  B1 = LD(baser, 5);  B2 = LD(baser, 6);  B3 = LD(baser, 7);
        CONS1(A0, 0) CONS1(A1, 1) CONS1(A2, 2) CONS1(A3, 3)
        A0 = LD(baser, 8);  A1 = LD(baser, 9);  A2 = LD(baser, 10); A3 = LD(baser, 11);
        CONS1(B0, 4) CONS1(B1, 5) CONS1(B2, 6) CONS1(B3, 7)
        B0 = LD(baser, 12); B1 = LD(baser, 13); B2 = LD(baser, 14); B3 = LD(baser, 15);
        CONS1(A0, 8) CONS1(A1, 9) CONS1(A2, 10) CONS1(A3, 11)
        if (r < IB - 1) {
            const float* basen = baser + (NN * DE);
            A0 = LD(basen, 0); A1 = LD(basen, 1); A2 = LD(basen, 2); A3 = LD(basen, 3);
        }
        CONS1(B0, 12) CONS1(B1, 13) CONS1(B2, 14) CONS1(B3, 15)
        #undef CONS1

        #pragma unroll
        for (int c = 0; c < 4; ++c) {
            s[c]  += __shfl_xor(s[c], 16);  s[c]  += __shfl_xor(s[c], 32);
            ms[c] += __shfl_xor(ms[c], 16); ms[c] += __shfl_xor(ms[c], 32);
            q[c]  += __shfl_xor(q[c], 16);  q[c]  += __shfl_xor(q[c], 32);
            mi[c] = fminf(mi[c], __shfl_xor(mi[c], 16));
            mi[c] = fminf(mi[c], __shfl_xor(mi[c], 32));
            ma[c] = fmaxf(ma[c], __shfl_xor(ma[c], 16));
            ma[c] = fmaxf(ma[c], __shfl_xor(ma[c], 32));
        }

        if (lane < 16) {
            float* p = partial[wv][lane];
            #pragma unroll
            for (int c = 0; c < 4; ++c) {
                p[c] = s[c]; p[4+c] = ms[c]; p[8+c] = q[c];
                p[12+c] = mi[c]; p[16+c] = ma[c];
            }
        }
        __syncthreads();

        if (t < 64) {
            const int d = t, dq2 = d >> 2, c = d & 3;
            float ss = 0.f, mss = 0.f, mq = 0.f, lmi = 1e30f, lma = -1e30f;
            #pragma unroll
            for (int w = 0; w < 4; ++w) {
                const float* p = partial[w][dq2];
                ss += p[c]; mss += p[4+c]; mq += p[8+c];
                lmi = fminf(lmi, p[12+c]); lma = fmaxf(lma, p[16+c]);
            }
            float m    = ss * inv_cnt;
            float stdv = mq * inv_cnt - 2.0f * m * (mss * inv_cnt) + m * m;
            z_lds[r][d] = m; z_lds[r][64+d] = lmi; z_lds[r][128+d] = lma; z_lds[r][192+d] = stdv;
        }
        __syncthreads();
    }
    #undef LD

    float acc0, acc1, acc2, acc3;
    {
        float bv = bias[t];
        acc0 = bv; acc1 = bv; acc2 = bv; acc3 = bv;
    }
    const float4* Wrow = (const float4*)(W + (size_t)t * FAN);
    #pragma unroll 8
    for (int f4 = 0; f4 < 64; ++f4) {
        float4 w4 = Wrow[f4];
        int f = 4 * f4;
        acc0 += z_lds[0][f]*w4.x + z_lds[0][f+1]*w4.y + z_lds[0][f+2]*w4.z + z_lds[0][f+3]*w4.w;
        acc1 += z_lds[1][f]*w4.x + z_lds[1][f+1]*w4.y + z_lds[1][f+2]*w4.z + z_lds[1][f+3]*w4.w;
        acc2 += z_lds[2][f]*w4.x + z_lds[2][f+1]*w4.y + z_lds[2][f+2]*w4.z + z_lds[2][f+3]*w4.w;
        acc3 += z_lds[3][f]*w4.x + z_lds[3][f+1]*w4.y + z_lds[3][f+2]*w4.z + z_lds[3][f+3]*w4.w;
    }
    out[(size_t)(g0 + 0) * DXX + t] = acc0;
    out[(size_t)(g0 + 1) * DXX + t] = acc1;
    out[(size_t)(g0 + 2) * DXX + t] = acc2;
    out[(size_t)(g0 + 3) * DXX + t] = acc3;
}

extern "C" void kernel_launch(void* const* d_in, const int* in_sizes, int n_in,
                              void* d_out, int out_size, void* d_ws, size_t ws_size,
                              hipStream_t stream) {
    const float*   E    = (const float*)d_in[0];
    const uint8_t* mraw = (const uint8_t*)d_in[1];
    const float*   W    = (const float*)d_in[2];
    const float*   bias = (const float*)d_in[3];
    float*         out  = (float*)d_out;

    const size_t wt_n   = (size_t)FAN * DXX;
    const size_t mask_n = (size_t)BSZ * NN;
    const size_t need   = (wt_n + mask_n) * sizeof(float);

    if (ws_size >= need) {
        float* WT    = (float*)d_ws;
        float* maskf = WT + wt_n;
        prep_kernel<<<FAN + 1, 256, 0, stream>>>(mraw, W, WT, maskf);
        etox_pc<<<(BSZ * NN) / IB, 320, 0, stream>>>(E, maskf, WT, bias, out);
    } else {
        etox_legacy<<<(BSZ * NN) / IB, 256, 0, stream>>>(E, mraw, W, bias, out);
    }
}

// Round 15
// 62.315 us; speedup vs baseline: 2.7023x; 2.7023x over previous
//
#include <hip/hip_runtime.h>
#include <cstdint>
#include <cstddef>

#define BSZ 16
#define NN  256
#define DE  64
#define DXX 256
#define FAN (4 * DE)   // 256
#define IB  8          // rows (b,i) per block

// ---------------------------------------------------------------------------
// Prologue: blocks 0..255 transpose W (DXX x FAN) -> WT (FAN x DXX, f32);
// block 256 detects mask dtype (u8/i32/f32) and normalizes to maskf[4096].
// ---------------------------------------------------------------------------
__global__ __launch_bounds__(256) void prep_kernel(
    const uint8_t* __restrict__ raw, const float* __restrict__ W,
    float* __restrict__ WT, float* __restrict__ maskf)
{
    const int t   = threadIdx.x;
    const int blk = blockIdx.x;
    if (blk < FAN) {
        WT[blk * DXX + t] = W[t * FAN + blk];   // WT[f][dx] = W[dx][f]
    } else {
        __shared__ int det[2];
        if (t == 0) { det[0] = 0; det[1] = 0; }
        __syncthreads();
        int s1 = 0, s23 = 0;
        const uint8_t* p = raw + t * 16;
        #pragma unroll
        for (int u = 0; u < 16; ++u) {
            int v = (int)p[u];
            int m4 = u & 3;
            if (m4 == 1) s1 += v; else if (m4 >= 2) s23 += v;
        }
        if (s1)  atomicAdd(&det[0], s1);
        if (s23) atomicAdd(&det[1], s23);
        __syncthreads();
        const int kind = (det[1] == 0) ? 1 : ((det[0] == 0) ? 2 : 0);  // 1=i32,2=f32,0=u8
        for (int idx = t; idx < BSZ * NN; idx += 256) {
            float mv;
            if (kind == 1)      mv = (((const int*)(const void*)raw)[idx] != 0) ? 1.f : 0.f;
            else if (kind == 2) mv = (((const float*)(const void*)raw)[idx] != 0.f) ? 1.f : 0.f;
            else                mv = (raw[idx] != 0) ? 1.f : 0.f;
            maskf[idx] = mv;
        }
    }
}

// ---------------------------------------------------------------------------
// Main kernel = R12 (best measured: 63.0us). R7 structure with IB=8: phase
// C's per-block 256 KB WT read amortized over 8 rows. Phase C in the
// epilogue with compile-time acc indexing; no global loads inside the
// streaming loop (R8/R10/R11/R14 lesson). TR=false: legacy fallback.
// ---------------------------------------------------------------------------
template <bool TR>
__global__ __launch_bounds__(256, 4) void etox_fused(
    const float* __restrict__ E, const uint8_t* __restrict__ raw,
    const float* __restrict__ maskf, const float* __restrict__ W,
    const float* __restrict__ WT, const float* __restrict__ bias,
    float* __restrict__ out)
{
    __shared__ float  m_lds[NN];
    __shared__ int    det[2];
    __shared__ float  cpart[4];
    __shared__ float  partial[4][16][20];   // [wave][dquad][acc] 5 KB
    __shared__ float  z_lds[IB][FAN];       // 8 KB
    __shared__ float4 part_c[4][IB][64];    // [wave][row][lane] 32 KB (TR only)

    const int t    = threadIdx.x;
    const int g0   = blockIdx.x * IB;       // global row = b*NN + i
    const int b    = g0 >> 8;
    const int wv   = t >> 6;
    const int lane = t & 63;

    // ---- phase A: mask row + count ----
    float mv;
    if (TR) {
        mv = maskf[b * NN + t];
    } else {
        if (t == 0) { det[0] = 0; det[1] = 0; }
        int s1 = 0, s23 = 0;
        const uint8_t* p = raw + t * 16;
        #pragma unroll
        for (int u = 0; u < 16; ++u) {
            int v = (int)p[u];
            int m4 = u & 3;
            if (m4 == 1) s1 += v; else if (m4 >= 2) s23 += v;
        }
        __syncthreads();
        if (s1)  atomicAdd(&det[0], s1);
        if (s23) atomicAdd(&det[1], s23);
        __syncthreads();
        const int kind = (det[1] == 0) ? 1 : ((det[0] == 0) ? 2 : 0);
        int idx = b * NN + t;
        if (kind == 1)      mv = (((const int*)(const void*)raw)[idx] != 0) ? 1.f : 0.f;
        else if (kind == 2) mv = (((const float*)(const void*)raw)[idx] != 0.f) ? 1.f : 0.f;
        else                mv = (raw[idx] != 0) ? 1.f : 0.f;
    }
    m_lds[t] = mv;
    unsigned long long bal = __ballot(mv != 0.f);
    if (lane == 0) cpart[wv] = (float)__popcll(bal);
    __syncthreads();
    const float inv_cnt = 1.0f / (cpart[0] + cpart[1] + cpart[2] + cpart[3]);

    // ---- phase B: pipelined one-pass reductions ----
    const int dq = t & 15;                 // d = 4*dq .. 4*dq+3
    const int jb = t >> 4;                 // j = jb + 16*k, k = 0..15
    const float* base0 = E + (size_t)g0 * (NN * DE) + (size_t)jb * DE + 4 * dq;

    #define LD(P, K) (*(const float4*)((P) + (size_t)(K) * (16 * DE)))
    float4 A0, A1, A2, A3, B0, B1, B2, B3;
    A0 = LD(base0, 0); A1 = LD(base0, 1); A2 = LD(base0, 2); A3 = LD(base0, 3);

    for (int r = 0; r < IB; ++r) {
        const float* baser = base0 + (size_t)r * (NN * DE);

        float s[4]  = {0.f, 0.f, 0.f, 0.f};
        float ms[4] = {0.f, 0.f, 0.f, 0.f};
        float q[4]  = {0.f, 0.f, 0.f, 0.f};
        float mi[4] = {1e30f, 1e30f, 1e30f, 1e30f};
        float ma[4] = {-1e30f, -1e30f, -1e30f, -1e30f};

        #define CONS1(V, KK) { \
            float mk = m_lds[jb + 16 * (KK)]; \
            bool on = (mk != 0.f); \
            float4 v = V; \
            s[0] += v.x; s[1] += v.y; s[2] += v.z; s[3] += v.w; \
            ms[0] = fmaf(mk, v.x, ms[0]); ms[1] = fmaf(mk, v.y, ms[1]); \
            ms[2] = fmaf(mk, v.z, ms[2]); ms[3] = fmaf(mk, v.w, ms[3]); \
            q[0] = fmaf(mk * v.x, v.x, q[0]); q[1] = fmaf(mk * v.y, v.y, q[1]); \
            q[2] = fmaf(mk * v.z, v.z, q[2]); q[3] = fmaf(mk * v.w, v.w, q[3]); \
            mi[0] = fminf(mi[0], on ? v.x : 1e30f); mi[1] = fminf(mi[1], on ? v.y : 1e30f); \
            mi[2] = fminf(mi[2], on ? v.z : 1e30f); mi[3] = fminf(mi[3], on ? v.w : 1e30f); \
            ma[0] = fmaxf(ma[0], on ? v.x : -1e30f); ma[1] = fmaxf(ma[1], on ? v.y : -1e30f); \
            ma[2] = fmaxf(ma[2], on ? v.z : -1e30f); ma[3] = fmaxf(ma[3], on ? v.w : -1e30f); \
        }

        B0 = LD(baser, 4);  B1 = LD(baser, 5);  B2 = LD(baser, 6);  B3 = LD(baser, 7);
        CONS1(A0, 0) CONS1(A1, 1) CONS1(A2, 2) CONS1(A3, 3)
        A0 = LD(baser, 8);  A1 = LD(baser, 9);  A2 = LD(baser, 10); A3 = LD(baser, 11);
        CONS1(B0, 4) CONS1(B1, 5) CONS1(B2, 6) CONS1(B3, 7)
        B0 = LD(baser, 12); B1 = LD(baser, 13); B2 = LD(baser, 14); B3 = LD(baser, 15);
        CONS1(A0, 8) CONS1(A1, 9) CONS1(A2, 10) CONS1(A3, 11)
        if (r < IB - 1) {   // prefetch next row's batch 0 across the barriers
            const float* basen = baser + (NN * DE);
            A0 = LD(basen, 0); A1 = LD(basen, 1); A2 = LD(basen, 2); A3 = LD(basen, 3);
        }
        CONS1(B0, 12) CONS1(B1, 13) CONS1(B2, 14) CONS1(B3, 15)
        #undef CONS1

        #pragma unroll
        for (int c = 0; c < 4; ++c) {
            s[c]  += __shfl_xor(s[c], 16);  s[c]  += __shfl_xor(s[c], 32);
            ms[c] += __shfl_xor(ms[c], 16); ms[c] += __shfl_xor(ms[c], 32);
            q[c]  += __shfl_xor(q[c], 16);  q[c]  += __shfl_xor(q[c], 32);
            mi[c] = fminf(mi[c], __shfl_xor(mi[c], 16));
            mi[c] = fminf(mi[c], __shfl_xor(mi[c], 32));
            ma[c] = fmaxf(ma[c], __shfl_xor(ma[c], 16));
            ma[c] = fmaxf(ma[c], __shfl_xor(ma[c], 32));
        }

        if (lane < 16) {
            float* p = partial[wv][lane];
            #pragma unroll
            for (int c = 0; c < 4; ++c) {
                p[c]      = s[c];
                p[4 + c]  = ms[c];
                p[8 + c]  = q[c];
                p[12 + c] = mi[c];
                p[16 + c] = ma[c];
            }
        }
        __syncthreads();

        if (t < 64) {
            const int d = t, dq2 = d >> 2, c = d & 3;
            float ss = 0.f, mss = 0.f, mq = 0.f, lmi = 1e30f, lma = -1e30f;
            #pragma unroll
            for (int w = 0; w < 4; ++w) {
                const float* p = partial[w][dq2];
                ss  += p[c];
                mss += p[4 + c];
                mq  += p[8 + c];
                lmi  = fminf(lmi, p[12 + c]);
                lma  = fmaxf(lma, p[16 + c]);
            }
            float m    = ss * inv_cnt;
            float stdv = mq * inv_cnt - 2.0f * m * (mss * inv_cnt) + m * m;
            z_lds[r][d]       = m;
            z_lds[r][64 + d]  = lmi;
            z_lds[r][128 + d] = lma;
            z_lds[r][192 + d] = stdv;
        }
        __syncthreads();   // partial[] reuse next row / z_lds complete
    }
    #undef LD

    // ---- phase C ----
    if (TR) {
        // wave wv owns f in [64*wv, 64*wv+64); lane owns dx = 4*lane..4*lane+3
        float4 acc[IB];
        #pragma unroll
        for (int r = 0; r < IB; ++r) acc[r] = make_float4(0.f, 0.f, 0.f, 0.f);

        const float4* WT4 = (const float4*)WT;   // WT[f][dx]: row f = 64 float4
        int f0 = 64 * wv;
        #pragma unroll 4
        for (int fg = 0; fg < 16; ++fg, f0 += 4) {
            float4 w0 = WT4[(size_t)(f0 + 0) * 64 + lane];
            float4 w1 = WT4[(size_t)(f0 + 1) * 64 + lane];
            float4 w2 = WT4[(size_t)(f0 + 2) * 64 + lane];
            float4 w3 = WT4[(size_t)(f0 + 3) * 64 + lane];
            #pragma unroll
            for (int r = 0; r < IB; ++r) {
                float4 z4 = *(const float4*)(&z_lds[r][f0]);
                acc[r].x = fmaf(z4.x, w0.x, fmaf(z4.y, w1.x, fmaf(z4.z, w2.x, fmaf(z4.w, w3.x, acc[r].x))));
                acc[r].y = fmaf(z4.x, w0.y, fmaf(z4.y, w1.y, fmaf(z4.z, w2.y, fmaf(z4.w, w3.y, acc[r].y))));
                acc[r].z = fmaf(z4.x, w0.z, fmaf(z4.y, w1.z, fmaf(z4.z, w2.z, fmaf(z4.w, w3.z, acc[r].z))));
                acc[r].w = fmaf(z4.x, w0.w, fmaf(z4.y, w1.w, fmaf(z4.z, w2.w, fmaf(z4.w, w3.w, acc[r].w))));
            }
        }
        #pragma unroll
        for (int r = 0; r < IB; ++r) part_c[wv][r][lane] = acc[r];
        __syncthreads();

        // epilogue: 512 (row,lane) outputs, 256 threads -> 2 passes
        #pragma unroll
        for (int pass = 0; pass < 2; ++pass) {
            const int row = (t >> 6) + 4 * pass, l2 = t & 63;
            float4 p0 = part_c[0][row][l2], p1 = part_c[1][row][l2];
            float4 p2 = part_c[2][row][l2], p3 = part_c[3][row][l2];
            float4 bv = *(const float4*)(bias + 4 * l2);
            float4 o;
            o.x = p0.x + p1.x + p2.x + p3.x + bv.x;
            o.y = p0.y + p1.y + p2.y + p3.y + bv.y;
            o.z = p0.z + p1.z + p2.z + p3.z + bv.z;
            o.w = p0.w + p1.w + p2.w + p3.w + bv.w;
            *(float4*)(out + (size_t)(g0 + row) * DXX + 4 * l2) = o;
        }
    } else {
        // legacy path: thread t = dx, f32 W direct
        float acc[IB];
        float bv = bias[t];
        #pragma unroll
        for (int r = 0; r < IB; ++r) acc[r] = bv;
        const float4* Wrow = (const float4*)(W + (size_t)t * FAN);
        #pragma unroll 8
        for (int f4 = 0; f4 < 64; ++f4) {
            float4 w4 = Wrow[f4];
            int f = 4 * f4;
            #pragma unroll
            for (int r = 0; r < IB; ++r) {
                acc[r] += z_lds[r][f] * w4.x + z_lds[r][f+1] * w4.y
                        + z_lds[r][f+2] * w4.z + z_lds[r][f+3] * w4.w;
            }
        }
        #pragma unroll
        for (int r = 0; r < IB; ++r)
            out[(size_t)(g0 + r) * DXX + t] = acc[r];
    }
}

extern "C" void kernel_launch(void* const* d_in, const int* in_sizes, int n_in,
                              void* d_out, int out_size, void* d_ws, size_t ws_size,
                              hipStream_t stream) {
    const float*   E    = (const float*)d_in[0];
    const uint8_t* mraw = (const uint8_t*)d_in[1];
    const float*   W    = (const float*)d_in[2];
    const float*   bias = (const float*)d_in[3];
    float*         out  = (float*)d_out;

    const size_t need = (size_t)FAN * DXX * sizeof(float) + (size_t)BSZ * NN * sizeof(float);
    if (ws_size >= need) {
        float* WT    = (float*)d_ws;
        float* maskf = (float*)d_ws + (size_t)FAN * DXX;
        prep_kernel<<<FAN + 1, 256, 0, stream>>>(mraw, W, WT, maskf);
        etox_fused<true><<<(BSZ * NN) / IB, 256, 0, stream>>>(E, mraw, maskf, W, WT, bias, out);
    } else {
        etox_fused<false><<<(BSZ * NN) / IB, 256, 0, stream>>>(E, mraw, nullptr, W, nullptr, bias, out);
    }
}